// Round 3
// baseline (57500.635 us; speedup 1.0000x reference)
//
#include <hip/hip_runtime.h>
#include <hip/hip_bf16.h>

typedef unsigned short u16;
typedef __attribute__((ext_vector_type(8))) short bf16x8;   // 8 bf16 = 4 VGPRs (guide §3)
typedef __attribute__((ext_vector_type(4))) float f32x4;

// ---------- helpers ----------
__device__ __forceinline__ float sigf(float x) { return 1.f / (1.f + __expf(-x)); }
__device__ __forceinline__ float tanhfast(float x) {
  // overflow-safe: exp argument always <= 0
  float ax = fabsf(x);
  float e = __expf(-2.f * ax);            // in (0,1]
  float t = (1.f - e) / (1.f + e);        // tanh(|x|)
  return copysignf(t, x);
}
__device__ __forceinline__ void async_cp16(void* lds, const void* g) {
  // global->LDS DMA, 16B/lane; LDS dest is wave-uniform base + lane*16 (guide §5)
  __builtin_amdgcn_global_load_lds(
      (__attribute__((address_space(1))) void*)const_cast<void*>(g),
      (__attribute__((address_space(3))) void*)lds, 16, 0, 0);
}
__device__ __forceinline__ unsigned pk2(float x, float y) {
  // packed f32x2 -> bf16x2 (RNE); .x lands in low 16 bits
  __hip_bfloat162 h = __float22bfloat162_rn(float2{x, y});
  union { __hip_bfloat162 h; unsigned u; } c;
  c.h = h;
  return c.u;
}
__device__ __forceinline__ bf16x8 frag_cvt(const float4* base, int u0, int u1) {
  // two swizzled float4 (8 consecutive k-values) -> bf16x8 fragment
  float4 a = base[u0], b = base[u1];
  union { unsigned u[4]; bf16x8 v; } pk;
  pk.u[0] = pk2(a.x, a.y);
  pk.u[1] = pk2(a.z, a.w);
  pk.u[2] = pk2(b.x, b.y);
  pk.u[3] = pk2(b.z, b.w);
  return pk.v;
}

// ---------- embedding gather: xf = embedding[sentence[:-1]] (f32, no rounding) ----------
__global__ __launch_bounds__(128) void embed_gather(const int* __restrict__ sent,
                                                    const float* __restrict__ emb,
                                                    float* __restrict__ xf) {
  int m = blockIdx.x;
  int idx = sent[m];
  float4 v = ((const float4*)(emb + (size_t)idx * 512))[threadIdx.x];
  ((float4*)(xf + (size_t)m * 512))[threadIdx.x] = v;
}

// ---------- MFMA GEMM, both operands f32 in memory, bf16 only in registers ----------
// C[m][n] = dot(A[m,:], B[n,:]) (+bias)(+relu), all f32 I/O.
// m97 structure: 128x128 tile, BK=32, 4 waves (2x2 quadrants), global_load_lds w16.
// Both tiles staged f32 [128][32] with XOR-preswizzled SOURCE + linear LDS dest +
// matching XOR on read (rule 21): row stride 128B would be 16-way conflicted;
// swizzle gives exactly 8 lanes per 16B bank-quad = the ds_read_b128 floor.
// Grid 1-D, m-tile-fastest: the 16 blocks sharing a B panel are dispatch-adjacent.
template <bool RELU, bool BIAS>
__global__ __launch_bounds__(256) void gemm_f32io(const float* __restrict__ A,
                                                  const float* __restrict__ B,
                                                  const float* __restrict__ bias,
                                                  float* __restrict__ C,
                                                  int M, int N, int K) {
  __shared__ float As[128 * 32];   // 16 KB
  __shared__ float Bs[128 * 32];   // 16 KB
  const int tid = threadIdx.x;
  const int lane = tid & 63;
  const int wv = tid >> 6;
  const int wr = wv >> 1, wc = wv & 1;
  const int m0 = (blockIdx.x & 15) * 128;   // m fastest (16 m-tiles for M=2047)
  const int n0 = (blockIdx.x >> 4) * 128;

  f32x4 acc[4][4];
#pragma unroll
  for (int i = 0; i < 4; ++i)
#pragma unroll
    for (int j = 0; j < 4; ++j) acc[i][j] = (f32x4){0.f, 0.f, 0.f, 0.f};

  // staging: 4 quarter-calls per operand; thread = (row sr in quarter, 16B unit su)
  const int sr = tid >> 3;                  // 0..31
  const int su = tid & 7;                   // 0..7
  const int sc = (su ^ (sr & 7)) * 4;       // preswizzled source col (f32 units)
  const float* gA[4];
#pragma unroll
  for (int q = 0; q < 4; ++q) {
    int r = m0 + sr + q * 32;
    if (r > M - 1) r = M - 1;               // clamp: dup row, discarded at C-write
    gA[q] = A + (size_t)r * K + sc;
  }
  const float* gB = B + (size_t)(n0 + sr) * K + sc;
  float* lA = &As[tid * 4];                 // linear dest (tid*16 bytes)
  float* lB = &Bs[tid * 4];

  // fragment read addressing (row&7 == rr&7 for all row = q*64 + rr + i*16)
  const int rr = lane & 15;
  const int g2 = (lane >> 4) * 2;           // first 16B unit of this lane's k-slice
  const int u0 = g2 ^ (rr & 7);
  const int u1 = (g2 + 1) ^ (rr & 7);
  const float4* fA = (const float4*)As + (size_t)(wr * 64 + rr) * 8;
  const float4* fB = (const float4*)Bs + (size_t)(wc * 64 + rr) * 8;

  for (int k0 = 0; k0 < K; k0 += 32) {
    __syncthreads();  // previous iter's ds_reads done before LDS overwrite
    async_cp16(lA,        gA[0] + k0);
    async_cp16(lA + 1024, gA[1] + k0);
    async_cp16(lA + 2048, gA[2] + k0);
    async_cp16(lA + 3072, gA[3] + k0);
    async_cp16(lB,        gB + k0);
    async_cp16(lB + 1024, gB + (size_t)32 * K + k0);
    async_cp16(lB + 2048, gB + (size_t)64 * K + k0);
    async_cp16(lB + 3072, gB + (size_t)96 * K + k0);
    __syncthreads();  // compiler drains vmcnt before s_barrier
    bf16x8 af[4], bg[4];
#pragma unroll
    for (int i = 0; i < 4; ++i) af[i] = frag_cvt(fA + i * 128, u0, u1);
#pragma unroll
    for (int j = 0; j < 4; ++j) bg[j] = frag_cvt(fB + j * 128, u0, u1);
#pragma unroll
    for (int i = 0; i < 4; ++i)
#pragma unroll
      for (int j = 0; j < 4; ++j)
        acc[i][j] = __builtin_amdgcn_mfma_f32_16x16x32_bf16(af[i], bg[j], acc[i][j], 0, 0, 0);
  }

  // C/D layout (HW-verified m89/m91): col = lane&15, row = (lane>>4)*4 + reg
  const int col_l = lane & 15;
  const int row_b = (lane >> 4) * 4;
#pragma unroll
  for (int j = 0; j < 4; ++j) {
    const int n = n0 + wc * 64 + j * 16 + col_l;
    const float bv = BIAS ? bias[n] : 0.f;
#pragma unroll
    for (int i = 0; i < 4; ++i) {
      const int mbase = m0 + wr * 64 + i * 16 + row_b;
#pragma unroll
      for (int q = 0; q < 4; ++q) {
        const int m = mbase + q;
        if (m < M) {
          float v = acc[i][j][q] + bv;
          if (RELU) v = fmaxf(v, 0.f);
          C[(size_t)m * N + n] = v;
        }
      }
    }
  }
}

// ---------- persistent dual-LSTM scan ----------
// 256 WGs (1/CU) x 256 thr. WG owns j in {4wg..4wg+3}: 32 gate-rows (en+cn), weights in VGPRs.
// thread = (pair, s): pair=(cell,gatepair,jl) in [0,16), s in [0,16): 2 rows x 64-elem segment.
// Per step: h broadcast via global (double-buffered) -> LDS; dots; shuffle-reduce; 4 lanes do
// the dual-cell update (c stays in registers); flag-array grid barrier (release/acquire, agent).
__global__ __launch_bounds__(256, 1) void scan_kernel(
    const float* __restrict__ gx_en, const float* __restrict__ gx_cn,
    const int* __restrict__ mask, const float* __restrict__ Wen,
    const float* __restrict__ Wcn, float* __restrict__ hbuf,
    float* __restrict__ outsb, unsigned* __restrict__ flags, int T) {
  const int wg = blockIdx.x;
  const int tid = threadIdx.x;
  const int pair = tid >> 4;
  const int s = tid & 15;
  const int cell = pair >> 3;
  const int gp = (pair >> 2) & 1;
  const int jl = pair & 3;
  const int gA = gp * 2, gB = gp * 2 + 1;
  const int j = (wg << 2) + jl;
  const int rA = (cell << 4) + (gA << 2) + jl;
  const int rB = (cell << 4) + (gB << 2) + jl;
  const float* Wb = cell ? Wcn : Wen;

  // weights pre-rotated by s so the LDS h-reads are bank-staggered (<=2-way = free, m136)
  float4 wA[16], wB[16];
  {
    const float4* A4 = (const float4*)(Wb + (((size_t)(gA << 10) + j) << 10)) + (s << 4);
    const float4* B4 = (const float4*)(Wb + (((size_t)(gB << 10) + j) << 10)) + (s << 4);
#pragma unroll
    for (int i = 0; i < 16; ++i) {
      wA[i] = A4[(i + s) & 15];
      wB[i] = B4[(i + s) & 15];
    }
  }

  __shared__ float sh[2048];      // h_en[1024], h_cn[1024]
  __shared__ float gsum[32];      // 32 gate dots
  __shared__ float pfg[2][32];    // prefetched gx, double-buffered
  __shared__ int pfm[2];          // prefetched mask

  auto gx_of = [&](int r, int tt) -> float {
    const float* g = (r < 16) ? gx_en : gx_cn;
    return g[(size_t)tt * 4096 + (size_t)(((r >> 2) & 3) << 10) + j];
  };

  float c_reg = 0.f;
  if (s == 1) { pfg[0][rA] = gx_of(rA, 0); pfg[0][rB] = gx_of(rB, 0); }
  if (tid == 0) pfm[0] = mask[0];
  __syncthreads();

  const float4* sh4 = (const float4*)sh;
  const int hbase = (cell << 8) + (s << 4);

  for (int t = 0; t < T; ++t) {
    const int cur = t & 1, nxt = cur ^ 1;
    const int tn = t + 1;
    // phase A: stage h (written remotely last step; fence at barrier made it visible)
    const float4* hs = ((const float4*)hbuf) + (cur << 9);
    float4 h0 = hs[tid];
    float4 h1 = hs[tid + 256];
    float pA = 0.f, pB = 0.f; int pm = 0;
    if (tn < T) {  // prefetch next step's gx/mask under the dot phase
      if (s == 1) { pA = gx_of(rA, tn); pB = gx_of(rB, tn); }
      if (tid == 0) pm = mask[tn];
    }
    ((float4*)sh)[tid] = h0;
    ((float4*)sh)[tid + 256] = h1;
    __syncthreads();
    // phase B: two 64-element dot segments per thread, weights in VGPRs
    float4 aA = {0, 0, 0, 0}, aB = {0, 0, 0, 0};
#pragma unroll
    for (int i = 0; i < 16; ++i) {
      float4 hv = sh4[hbase + ((i + s) & 15)];
      aA.x += wA[i].x * hv.x; aA.y += wA[i].y * hv.y;
      aA.z += wA[i].z * hv.z; aA.w += wA[i].w * hv.w;
      aB.x += wB[i].x * hv.x; aB.y += wB[i].y * hv.y;
      aB.z += wB[i].z * hv.z; aB.w += wB[i].w * hv.w;
    }
    float sA = aA.x + aA.y + aA.z + aA.w;
    float sB = aB.x + aB.y + aB.z + aB.w;
#pragma unroll
    for (int md = 1; md < 16; md <<= 1) {
      sA += __shfl_xor(sA, md, 64);
      sB += __shfl_xor(sB, md, 64);
    }
    if (s == 0) { gsum[rA] = sA; gsum[rB] = sB; }
    if (tn < T) {
      if (s == 1) { pfg[nxt][rA] = pA; pfg[nxt][rB] = pB; }
      if (tid == 0) pfm[nxt] = pm;
    }
    __syncthreads();
    // phase C: dual-cell update, one lane per owned j (lanes 0,16,32,48 of wave 0)
    if (s == 0 && pair < 4) {
      float u[4], v[4], ge[4], gc[4];
#pragma unroll
      for (int g = 0; g < 4; ++g) {
        u[g] = gsum[(g << 2) + pair];
        v[g] = gsum[16 + (g << 2) + pair];
        ge[g] = pfg[cur][(g << 2) + pair];
        gc[g] = pfg[cur][16 + (g << 2) + pair];
      }
      const int men = pfm[cur];
      // branch A: cell(ge+u, c) -> cell(v, cA1)   (gate order i,f,g,o per jnp.split)
      float a0 = ge[0] + u[0], a1 = ge[1] + u[1], a2 = ge[2] + u[2], a3 = ge[3] + u[3];
      float cA1 = sigf(a1) * c_reg + sigf(a0) * tanhfast(a2);
      float hAen = sigf(a3) * tanhfast(cA1);
      float cA2 = sigf(v[1]) * cA1 + sigf(v[0]) * tanhfast(v[2]);
      float hAcn = sigf(v[3]) * tanhfast(cA2);
      // branch B: cell(gc+v, c) -> cell(u, cB1)
      float b0 = gc[0] + v[0], b1 = gc[1] + v[1], b2 = gc[2] + v[2], b3 = gc[3] + v[3];
      float cB1 = sigf(b1) * c_reg + sigf(b0) * tanhfast(b2);
      float hBcn = sigf(b3) * tanhfast(cB1);
      float cB2 = sigf(u[1]) * cB1 + sigf(u[0]) * tanhfast(u[2]);
      float hBen = sigf(u[3]) * tanhfast(cB2);
      const bool en = men > 0;
      float hen2 = en ? hAen : hBen;
      float hcn2 = en ? hAcn : hBcn;
      c_reg = en ? cA2 : cB2;
      const int jj = (wg << 2) + pair;
      hbuf[(nxt << 11) + jj] = hen2;
      hbuf[(nxt << 11) + 1024 + jj] = hcn2;
      outsb[(size_t)t * 1024 + jj] = hen2 + hcn2;
    }
    // grid sync: per-WG step-stamp flags (release) + all-flags spin (acquire)
    if (tn < T) {
      __syncthreads();  // all h stores complete (vmcnt drained at barrier)
      if (tid == 0) {
        __threadfence();  // flush toward coherence point
        __hip_atomic_store(&flags[wg], (unsigned)tn, __ATOMIC_RELEASE, __HIP_MEMORY_SCOPE_AGENT);
      }
      int ok = 0, it = 0;
      do {
        unsigned f = __hip_atomic_load(&flags[tid], __ATOMIC_RELAXED, __HIP_MEMORY_SCOPE_AGENT);
        ok = (f >= (unsigned)tn);
        ++it;
      } while (!__syncthreads_and(ok) && it < 8000);  // cap: liveness guard, never hit if correct
      __threadfence();  // acquire: invalidate stale caches before reading remote h
    }
  }
}

// ---------- launcher ----------
extern "C" void kernel_launch(void* const* d_in, const int* in_sizes, int n_in,
                              void* d_out, int out_size, void* d_ws, size_t ws_size,
                              hipStream_t stream) {
  (void)in_sizes; (void)n_in; (void)out_size;
  const int* sentence = (const int*)d_in[0];
  const int* mask     = (const int*)d_in[1];
  const float* emb    = (const float*)d_in[2];
  const float* W_ih_en = (const float*)d_in[3];
  const float* W_hh_en = (const float*)d_in[4];
  const float* W_ih_cn = (const float*)d_in[5];
  const float* W_hh_cn = (const float*)d_in[6];
  const float* fc_w1  = (const float*)d_in[7];
  const float* fc_b1  = (const float*)d_in[8];
  const float* fc_w2  = (const float*)d_in[9];
  const float* fc_b2  = (const float*)d_in[10];
  float* outp = (float*)d_out;

  const int T = 2047;  // S-1

  // workspace: flags[256] | hbuf[2][2048] f32 | hid f32  (~8.4 MB requirement)
  char* ws = (char*)d_ws;
  unsigned* flags = (unsigned*)ws;            // [0, 1024)
  float* hbuf     = (float*)(ws + 1024);      // [1024, 17408)
  float* hidf     = (float*)(ws + 17408);     // T*1024 f32
  const size_t ws_need = 17408 + (size_t)T * 1024 * 4;
  if (ws_size < ws_need) return;

  // transient scratch inside d_out (262 MB; fc2 reads nothing from d_out and
  // overwrites all of it last): xf | gxen | gxcn | outs  (~79.7 MB, all f32)
  char* ob = (char*)d_out;
  float* xf    = (float*)(ob);
  float* gxen  = (float*)(ob + (size_t)T * 512 * 4);
  float* gxcn  = (float*)(ob + (size_t)T * 512 * 4 + (size_t)T * 4096 * 4);
  float* outsb = (float*)(ob + (size_t)T * 512 * 4 + (size_t)T * 4096 * 8);

  hipMemsetAsync(d_ws, 0, 17408, stream);  // zero flags + h0/c0 state

  // x = embedding[sentence[:-1]] (f32 gather, no rounding)
  embed_gather<<<T, 128, 0, stream>>>(sentence, emb, xf);

  // gx_en / gx_cn = x @ W_ih^T (f32 in/out; bf16 only inside MFMA registers)
  gemm_f32io<false, false><<<32 * 16, 256, 0, stream>>>(xf, W_ih_en, nullptr, gxen, T, 4096, 512);
  gemm_f32io<false, false><<<32 * 16, 256, 0, stream>>>(xf, W_ih_cn, nullptr, gxcn, T, 4096, 512);

  // persistent scan (cooperative: guarantees 256-WG co-residency for the grid barrier)
  {
    const float* a0 = gxen; const float* a1 = gxcn; const int* a2 = mask;
    const float* a3 = W_hh_en; const float* a4 = W_hh_cn;
    float* a5 = hbuf; float* a6 = outsb; unsigned* a7 = flags; int a8 = T;
    void* kargs[] = {&a0, &a1, &a2, &a3, &a4, &a5, &a6, &a7, &a8};
    hipLaunchCooperativeKernel((const void*)scan_kernel, dim3(256), dim3(256), kargs, 0, stream);
  }

  // hid = relu(outs @ fc_w1^T + b1) -> f32 ws ; logits = hid @ fc_w2^T + b2 -> f32 d_out
  gemm_f32io<true, true><<<8 * 16, 256, 0, stream>>>(outsb, fc_w1, fc_b1, hidf, T, 1024, 1024);
  gemm_f32io<false, true><<<250 * 16, 256, 0, stream>>>(hidf, fc_w2, fc_b2, outp, T, 32000, 1024);
}